// Round 3
// baseline (273.664 us; speedup 1.0000x reference)
//
#include <hip/hip_runtime.h>
#include <math.h>

#define B_ 32
#define C_ 256
#define HW_ 3136      // 56*56
#define HW4_ 784      // HW/4 (float4 = 16B chunks)
#define G_ 32
#define EPS_ 1e-5f

// ws layout (floats): [0..31] alphaacc  [32..287] gs  [288..543] gsh
//                     [544..799] ms  [800..1055] msh
#define WS_ALPHA 0
#define WS_GS    32
#define WS_GSH   (32 + 256)
#define WS_MS    (32 + 512)
#define WS_MSH   (32 + 768)

// K1: one block per (b,c) plane.
//  - pools the plane, atomicAdd(mean * alpha_w[c]) into alphaacc[b]
//  - blocks 0..255 (b==0) additionally fold the batch-independent affine
//    params for channel c: gs/gsh (global BN) and ms/msh (group mean).
__global__ __launch_bounds__(256) void pool_fold_kernel(
    const float* __restrict__ x,
    const float* __restrict__ alpha_w,
    const float* __restrict__ g_w, const float* __restrict__ g_b,
    const float* __restrict__ g_rm, const float* __restrict__ g_rv,
    const float* __restrict__ grp_w, const float* __restrict__ grp_b,
    const float* __restrict__ grp_rm, const float* __restrict__ grp_rv,
    float* __restrict__ ws) {
    const int bc = blockIdx.x;
    const int c  = bc & (C_ - 1);
    const int b  = bc >> 8;
    const int tid = threadIdx.x;

    const float4* __restrict__ p = (const float4*)(x + (size_t)bc * HW_);
    float s = 0.f;
    for (int i = tid; i < HW4_; i += 256) {
        float4 v = p[i];
        s += v.x + v.y + v.z + v.w;
    }
    #pragma unroll
    for (int off = 32; off; off >>= 1) s += __shfl_down(s, off);
    __shared__ float red[4];
    const int lane = tid & 63, wv = tid >> 6;
    if (lane == 0) red[wv] = s;
    __syncthreads();
    if (tid == 0) {
        float mean = (red[0] + red[1] + red[2] + red[3]) * (1.f / HW_);
        atomicAdd(ws + WS_ALPHA + b, mean * alpha_w[c]);
    }

    // batch-independent param fold, done once (by the b==0 blocks)
    if (b == 0 && tid < G_) {
        const int g = tid;
        float sg = grp_w[g * C_ + c] * rsqrtf(grp_rv[g * C_ + c] + EPS_);
        float sh = grp_b[g * C_ + c] - grp_rm[g * C_ + c] * sg;
        // reduce across the 32 lanes (all in wave 0)
        #pragma unroll
        for (int off = 16; off; off >>= 1) {
            sg += __shfl_down(sg, off);
            sh += __shfl_down(sh, off);
        }
        if (g == 0) {
            ws[WS_MS  + c] = sg * (1.f / G_);
            ws[WS_MSH + c] = sh * (1.f / G_);
            float gsv = g_w[c] * rsqrtf(g_rv[c] + EPS_);
            ws[WS_GS  + c] = gsv;
            ws[WS_GSH + c] = g_b[c] - g_rm[c] * gsv;
        }
    }
}

// K3: one block per (b,c) plane; folds alpha + params inline (all L2-hot),
// applies out = x*scale + shift with non-temporal stores (out never re-read;
// keep x L3-resident instead).
__global__ __launch_bounds__(256) void apply_kernel(
    const float* __restrict__ x,
    const float* __restrict__ ws,
    const float* __restrict__ alpha_b,
    float* __restrict__ out) {
    const int bc = blockIdx.x;
    const int c  = bc & (C_ - 1);
    const int b  = bc >> 8;

    // every thread computes the (identical) scale/shift — 6 broadcast loads
    float z  = ws[WS_ALPHA + b] + alpha_b[0];
    float a  = 1.f / (1.f + __expf(-z));
    float gs  = ws[WS_GS  + c], gsh = ws[WS_GSH + c];
    float ms  = ws[WS_MS  + c], msh = ws[WS_MSH + c];
    const float sc = fmaf(a, ms - gs, gs);    // (1-a)*gs + a*ms
    const float sh = fmaf(a, msh - gsh, gsh);

    const float4* __restrict__ px = (const float4*)(x + (size_t)bc * HW_);
    float4* __restrict__ po = (float4*)(out + (size_t)bc * HW_);
    for (int i = threadIdx.x; i < HW4_; i += 256) {
        float4 v = px[i];
        float4 r;
        r.x = fmaf(v.x, sc, sh);
        r.y = fmaf(v.y, sc, sh);
        r.z = fmaf(v.z, sc, sh);
        r.w = fmaf(v.w, sc, sh);
        __builtin_nontemporal_store(r.x, &po[i].x);
        __builtin_nontemporal_store(r.y, &po[i].y);
        __builtin_nontemporal_store(r.z, &po[i].z);
        __builtin_nontemporal_store(r.w, &po[i].w);
    }
}

extern "C" void kernel_launch(void* const* d_in, const int* in_sizes, int n_in,
                              void* d_out, int out_size, void* d_ws, size_t ws_size,
                              hipStream_t stream) {
    const float* x       = (const float*)d_in[0];
    const float* alpha_w = (const float*)d_in[2];
    const float* alpha_b = (const float*)d_in[3];
    const float* g_w     = (const float*)d_in[4];
    const float* g_b     = (const float*)d_in[5];
    const float* g_rm    = (const float*)d_in[6];
    const float* g_rv    = (const float*)d_in[7];
    const float* grp_w   = (const float*)d_in[8];
    const float* grp_b   = (const float*)d_in[9];
    const float* grp_rm  = (const float*)d_in[10];
    const float* grp_rv  = (const float*)d_in[11];
    float* out = (float*)d_out;
    float* ws  = (float*)d_ws;

    // zero the alpha accumulators (ws is poisoned 0xAA before every launch)
    hipMemsetAsync(ws, 0, B_ * sizeof(float), stream);

    pool_fold_kernel<<<B_ * C_, 256, 0, stream>>>(x, alpha_w,
                                                  g_w, g_b, g_rm, g_rv,
                                                  grp_w, grp_b, grp_rm, grp_rv,
                                                  ws);
    apply_kernel<<<B_ * C_, 256, 0, stream>>>(x, ws, alpha_b, out);
}

// Round 4
// 214.363 us; speedup vs baseline: 1.2766x; 1.2766x over previous
//
#include <hip/hip_runtime.h>
#include <math.h>

#define B_ 32
#define C_ 256
#define HW_ 3136      // 56*56
#define HW4_ 784      // HW/4 (float4 = 16B chunks)
#define G_ 32
#define EPS_ 1e-5f

// ws layout (floats):
//   [0 .. 8191]            pooled[b*C + c]
//   [8192 .. 8447]         gs[c]
//   [8448 .. 8703]         gsh[c]
//   [8704 .. 8959]         ms[c]
//   [8960 .. 9215]         msh[c]
#define WS_POOL 0
#define WS_GS   (B_ * C_)
#define WS_GSH  (B_ * C_ + C_)
#define WS_MS   (B_ * C_ + 2 * C_)
#define WS_MSH  (B_ * C_ + 3 * C_)

// K1: one block per (b,c) plane — pooled mean (non-atomic write).
// The b==0 blocks additionally fold the batch-independent affine params
// for their channel c (gs/gsh global-BN, ms/msh group mean).
__global__ __launch_bounds__(256) void pool_kernel(
    const float* __restrict__ x,
    const float* __restrict__ g_w, const float* __restrict__ g_b,
    const float* __restrict__ g_rm, const float* __restrict__ g_rv,
    const float* __restrict__ grp_w, const float* __restrict__ grp_b,
    const float* __restrict__ grp_rm, const float* __restrict__ grp_rv,
    float* __restrict__ ws) {
    const int bc = blockIdx.x;
    const int c  = bc & (C_ - 1);
    const int b  = bc >> 8;
    const int tid = threadIdx.x;

    const float4* __restrict__ p = (const float4*)(x + (size_t)bc * HW_);
    float s = 0.f;
    for (int i = tid; i < HW4_; i += 256) {
        float4 v = p[i];
        s += v.x + v.y + v.z + v.w;
    }
    #pragma unroll
    for (int off = 32; off; off >>= 1) s += __shfl_down(s, off);
    __shared__ float red[4];
    const int lane = tid & 63, wv = tid >> 6;
    if (lane == 0) red[wv] = s;
    __syncthreads();
    if (tid == 0) {
        ws[WS_POOL + bc] = (red[0] + red[1] + red[2] + red[3]) * (1.f / HW_);
    }

    // batch-independent param fold, once (b==0 blocks), wave 0 only
    if (b == 0 && tid < G_) {
        const int g = tid;
        float sg = grp_w[g * C_ + c] * rsqrtf(grp_rv[g * C_ + c] + EPS_);
        float sh = grp_b[g * C_ + c] - grp_rm[g * C_ + c] * sg;
        #pragma unroll
        for (int off = 16; off; off >>= 1) {
            sg += __shfl_down(sg, off);
            sh += __shfl_down(sh, off);
        }
        if (g == 0) {
            ws[WS_MS  + c] = sg * (1.f / G_);
            ws[WS_MSH + c] = sh * (1.f / G_);
            float gsv = g_w[c] * rsqrtf(g_rv[c] + EPS_);
            ws[WS_GS  + c] = gsv;
            ws[WS_GSH + c] = g_b[c] - g_rm[c] * gsv;
        }
    }
}

// K2: one block per (b,c) plane. Prologue recomputes alpha[b] from the
// L2-hot pooled row (256-wide dot + sigmoid, deterministic, no atomics),
// then streams out = x*scale + shift with non-temporal stores.
__global__ __launch_bounds__(256) void apply_kernel(
    const float* __restrict__ x,
    const float* __restrict__ ws,
    const float* __restrict__ alpha_w,
    const float* __restrict__ alpha_b,
    float* __restrict__ out) {
    const int bc = blockIdx.x;
    const int c  = bc & (C_ - 1);
    const int b  = bc >> 8;
    const int tid = threadIdx.x;

    // alpha[b] = sigmoid(dot(pooled[b,:], alpha_w) + alpha_b)
    float s = ws[WS_POOL + b * C_ + tid] * alpha_w[tid];
    #pragma unroll
    for (int off = 32; off; off >>= 1) s += __shfl_down(s, off);
    __shared__ float red[4];
    __shared__ float a_sh;
    const int lane = tid & 63, wv = tid >> 6;
    if (lane == 0) red[wv] = s;
    __syncthreads();
    if (tid == 0) {
        float z = red[0] + red[1] + red[2] + red[3] + alpha_b[0];
        a_sh = 1.f / (1.f + __expf(-z));
    }
    __syncthreads();
    const float a = a_sh;

    const float gs  = ws[WS_GS  + c], gsh = ws[WS_GSH + c];
    const float ms  = ws[WS_MS  + c], msh = ws[WS_MSH + c];
    const float sc = fmaf(a, ms - gs, gs);      // (1-a)*gs + a*ms
    const float sh = fmaf(a, msh - gsh, gsh);

    const float4* __restrict__ px = (const float4*)(x + (size_t)bc * HW_);
    float4* __restrict__ po = (float4*)(out + (size_t)bc * HW_);
    for (int i = tid; i < HW4_; i += 256) {
        float4 v = px[i];
        float4 r;
        r.x = fmaf(v.x, sc, sh);
        r.y = fmaf(v.y, sc, sh);
        r.z = fmaf(v.z, sc, sh);
        r.w = fmaf(v.w, sc, sh);
        __builtin_nontemporal_store(r.x, &po[i].x);
        __builtin_nontemporal_store(r.y, &po[i].y);
        __builtin_nontemporal_store(r.z, &po[i].z);
        __builtin_nontemporal_store(r.w, &po[i].w);
    }
}

extern "C" void kernel_launch(void* const* d_in, const int* in_sizes, int n_in,
                              void* d_out, int out_size, void* d_ws, size_t ws_size,
                              hipStream_t stream) {
    const float* x       = (const float*)d_in[0];
    const float* alpha_w = (const float*)d_in[2];
    const float* alpha_b = (const float*)d_in[3];
    const float* g_w     = (const float*)d_in[4];
    const float* g_b     = (const float*)d_in[5];
    const float* g_rm    = (const float*)d_in[6];
    const float* g_rv    = (const float*)d_in[7];
    const float* grp_w   = (const float*)d_in[8];
    const float* grp_b   = (const float*)d_in[9];
    const float* grp_rm  = (const float*)d_in[10];
    const float* grp_rv  = (const float*)d_in[11];
    float* out = (float*)d_out;
    float* ws  = (float*)d_ws;

    pool_kernel<<<B_ * C_, 256, 0, stream>>>(x,
                                             g_w, g_b, g_rm, g_rv,
                                             grp_w, grp_b, grp_rm, grp_rv,
                                             ws);
    apply_kernel<<<B_ * C_, 256, 0, stream>>>(x, ws, alpha_w, alpha_b, out);
}